// Round 1
// baseline (129.079 us; speedup 1.0000x reference)
//
#include <hip/hip_runtime.h>
#include <math.h>

#define N_TOK 8192
#define DIM   1024
#define NE    8
#define NR    16
#define NO    3072
#define OUT_ELEMS (N_TOK * NO)   // 25165824

__device__ __forceinline__ float softplusf(float z) {
  return z > 0.f ? z + log1pf(expf(-z)) : log1pf(expf(z));
}
__device__ __forceinline__ float ncdf(float z) {
  return 0.5f * erfcf(-z * 0.70710678118654752f);
}

#define FMA4(A, S, W) { (A).x = fmaf((S),(W).x,(A).x); (A).y = fmaf((S),(W).y,(A).y); \
                        (A).z = fmaf((S),(W).z,(A).z); (A).w = fmaf((S),(W).w,(A).w); }
#define DOT4(X, A) fmaf((X).x,(A).x, fmaf((X).y,(A).y, fmaf((X).z,(A).z, (X).w*(A).w)))
#define RED4(A, OFF) { (A).x += __shfl_xor((A).x, OFF); (A).y += __shfl_xor((A).y, OFF); \
                       (A).z += __shfl_xor((A).z, OFF); (A).w += __shfl_xor((A).w, OFF); }

// ---------------------------------------------------------------------------
// Kernel A: gating. 16 tokens/block, 256 threads = ksub(16) x sg(4) x wave(4 tok).
// logits16 = x @ [w_gate | w_noise]; then top-2, expert id, prob, block partials.
// ---------------------------------------------------------------------------
__global__ __launch_bounds__(256) void kA(const float* __restrict__ x,
    const float* __restrict__ wg, const float* __restrict__ wn,
    const float* __restrict__ nz, int* __restrict__ eid, float* __restrict__ part) {
  __shared__ float lg_lds[16][20];
  int t = threadIdx.x;
  int n0 = blockIdx.x << 4;
  int ksub = t & 15, sg = (t >> 4) & 3, tokg = t >> 6;
  const float* wbase = (sg < 2 ? wg : wn) + ((sg & 1) << 2);
  const float* x0 = x + (size_t)(n0 + (tokg << 2) + 0) * DIM;
  const float* x1 = x0 + DIM;
  const float* x2 = x1 + DIM;
  const float* x3 = x2 + DIM;
  float4 acc0 = make_float4(0.f,0.f,0.f,0.f), acc1 = acc0, acc2 = acc0, acc3 = acc0;
  #pragma unroll 4
  for (int m = 0; m < 16; ++m) {
    int k = (ksub << 2) + (m << 6);
    float4 xv0 = *(const float4*)(x0 + k);
    float4 xv1 = *(const float4*)(x1 + k);
    float4 xv2 = *(const float4*)(x2 + k);
    float4 xv3 = *(const float4*)(x3 + k);
    float4 w0 = *(const float4*)(wbase + (k + 0) * NE);
    float4 w1 = *(const float4*)(wbase + (k + 1) * NE);
    float4 w2 = *(const float4*)(wbase + (k + 2) * NE);
    float4 w3 = *(const float4*)(wbase + (k + 3) * NE);
    FMA4(acc0, xv0.x, w0); FMA4(acc0, xv0.y, w1); FMA4(acc0, xv0.z, w2); FMA4(acc0, xv0.w, w3);
    FMA4(acc1, xv1.x, w0); FMA4(acc1, xv1.y, w1); FMA4(acc1, xv1.z, w2); FMA4(acc1, xv1.w, w3);
    FMA4(acc2, xv2.x, w0); FMA4(acc2, xv2.y, w1); FMA4(acc2, xv2.z, w2); FMA4(acc2, xv2.w, w3);
    FMA4(acc3, xv3.x, w0); FMA4(acc3, xv3.y, w1); FMA4(acc3, xv3.z, w2); FMA4(acc3, xv3.w, w3);
  }
  #pragma unroll
  for (int off = 1; off <= 8; off <<= 1) {
    RED4(acc0, off); RED4(acc1, off); RED4(acc2, off); RED4(acc3, off);
  }
  if ((t & 15) == 0) {
    int tb = tokg << 2, sc = sg << 2;
    *(float4*)&lg_lds[tb + 0][sc] = acc0;
    *(float4*)&lg_lds[tb + 1][sc] = acc1;
    *(float4*)&lg_lds[tb + 2][sc] = acc2;
    *(float4*)&lg_lds[tb + 3][sc] = acc3;
  }
  __syncthreads();
  if (t < 16) {
    int n = n0 + t;
    float cl[8], st[8], lg[8];
    #pragma unroll
    for (int e = 0; e < 8; ++e) cl[e] = lg_lds[t][e];
    #pragma unroll
    for (int e = 0; e < 8; ++e) {
      st[e] = softplusf(lg_lds[t][8 + e]) + 0.01f;
      lg[e] = fmaf(nz[(size_t)n * NE + e], st[e], cl[e]);
    }
    float m1 = -1e30f, m2 = -1e30f; int idx = 0;
    #pragma unroll
    for (int e = 0; e < 8; ++e) {
      float v = lg[e];
      if (v > m1)      { m2 = m1; m1 = v; idx = e; }
      else if (v > m2) { m2 = v; }
    }
    eid[n] = idx;
    float pr[8], cw[8];
    #pragma unroll
    for (int e = 0; e < 8; ++e) {
      float thr = (lg[e] > m2) ? m2 : m1;
      pr[e] = ncdf((cl[e] - thr) / st[e]);
    }
    #pragma unroll
    for (int e = 0; e < 8; ++e) cw[e] = (float)__popcll(__ballot(idx == e));
    #pragma unroll
    for (int e = 0; e < 8; ++e) {
      #pragma unroll
      for (int off = 1; off <= 8; off <<= 1) pr[e] += __shfl_xor(pr[e], off);
    }
    if (t == 0) {
      #pragma unroll
      for (int e = 0; e < 8; ++e) {
        part[blockIdx.x * 16 + e]     = cw[e];
        part[blockIdx.x * 16 + 8 + e] = pr[e];
      }
    }
  }
}

// ---------------------------------------------------------------------------
// Kernel B: reduce 512x16 partials -> importance[8], load[8] into d_out tail;
// also counts (int) and zero fill counters.
// ---------------------------------------------------------------------------
__global__ __launch_bounds__(256) void kB(const float* __restrict__ part,
    float* __restrict__ outIL, int* __restrict__ counts, int* __restrict__ fill) {
  __shared__ float red[16][16];
  int t = threadIdx.x;
  int s = t & 15, g = t >> 4;
  float sum = 0.f;
  for (int j = 0; j < 32; ++j) sum += part[(g + 16 * j) * 16 + s];
  red[g][s] = sum;
  __syncthreads();
  if (t < 16) {
    float tot = 0.f;
    #pragma unroll
    for (int gg = 0; gg < 16; ++gg) tot += red[gg][t];
    outIL[t] = tot;                       // [0..7] importance, [8..15] load
    if (t < 8) { counts[t] = (int)(tot + 0.5f); fill[t] = 0; }
  }
}

// ---------------------------------------------------------------------------
// Kernel C: bucket tokens by expert (two-level: LDS hist + 8 global atomics).
// ---------------------------------------------------------------------------
__global__ __launch_bounds__(256) void kC(const int* __restrict__ eid,
    const int* __restrict__ counts, int* __restrict__ fill, int* __restrict__ bucket) {
  __shared__ int lcnt[8], lbase[8];
  int t = threadIdx.x;
  if (t < 8) lcnt[t] = 0;
  __syncthreads();
  int n = blockIdx.x * 256 + t;
  int e = eid[n];
  int rank = atomicAdd(&lcnt[e], 1);
  __syncthreads();
  if (t < 8) lbase[t] = atomicAdd(&fill[t], lcnt[t]);
  __syncthreads();
  int off = 0;
  #pragma unroll
  for (int i = 0; i < 8; ++i) if (i < e) off += counts[i];
  bucket[off + lbase[e] + rank] = n;
}

// ---------------------------------------------------------------------------
// Kernel D: h_sorted[p] = lora_a[e] @ x[bucket[p]].  32 tokens/tile.
// threads = dsub(8) x rg(4) x tokg(8); per-thread 4tok x 4r over 128 d.
// ---------------------------------------------------------------------------
__global__ __launch_bounds__(256) void kD(const float* __restrict__ x,
    const float* __restrict__ la, const int* __restrict__ counts,
    const int* __restrict__ bucket, float* __restrict__ h) {
  __shared__ int toks[32];
  int tile = blockIdx.x;
  int e = -1, jt = 0, off = 0;
  { int tot = 0, o = 0;
    #pragma unroll
    for (int i = 0; i < 8; ++i) {
      int c = counts[i]; int nt = (c + 31) >> 5;
      if (e < 0 && tile < tot + nt) { e = i; jt = tile - tot; off = o; }
      tot += nt; o += c;
    } }
  if (e < 0) return;
  int cnt = counts[e];
  int p0 = off + (jt << 5);
  int valid = min(32, cnt - (jt << 5));
  int t = threadIdx.x;
  if (t < 32) toks[t] = bucket[p0 + min(t, valid - 1)];
  __syncthreads();
  int dsub = t & 7, rg = (t >> 3) & 3, tokg = t >> 5;
  const float* a0 = la + (size_t)(e * NR + (rg << 2)) * DIM;
  const float* a1 = a0 + DIM;
  const float* a2 = a1 + DIM;
  const float* a3 = a2 + DIM;
  int tb = tokg << 2;
  const float* xr0 = x + (size_t)toks[tb + 0] * DIM;
  const float* xr1 = x + (size_t)toks[tb + 1] * DIM;
  const float* xr2 = x + (size_t)toks[tb + 2] * DIM;
  const float* xr3 = x + (size_t)toks[tb + 3] * DIM;
  float4 acc0 = make_float4(0.f,0.f,0.f,0.f), acc1 = acc0, acc2 = acc0, acc3 = acc0;
  #pragma unroll 8
  for (int i = 0; i < 32; ++i) {
    int d = (dsub << 7) + (i << 2);
    float4 av0 = *(const float4*)(a0 + d);
    float4 av1 = *(const float4*)(a1 + d);
    float4 av2 = *(const float4*)(a2 + d);
    float4 av3 = *(const float4*)(a3 + d);
    float4 xv;
    xv = *(const float4*)(xr0 + d);
    acc0.x += DOT4(xv, av0); acc0.y += DOT4(xv, av1); acc0.z += DOT4(xv, av2); acc0.w += DOT4(xv, av3);
    xv = *(const float4*)(xr1 + d);
    acc1.x += DOT4(xv, av0); acc1.y += DOT4(xv, av1); acc1.z += DOT4(xv, av2); acc1.w += DOT4(xv, av3);
    xv = *(const float4*)(xr2 + d);
    acc2.x += DOT4(xv, av0); acc2.y += DOT4(xv, av1); acc2.z += DOT4(xv, av2); acc2.w += DOT4(xv, av3);
    xv = *(const float4*)(xr3 + d);
    acc3.x += DOT4(xv, av0); acc3.y += DOT4(xv, av1); acc3.z += DOT4(xv, av2); acc3.w += DOT4(xv, av3);
  }
  #pragma unroll
  for (int off2 = 1; off2 <= 4; off2 <<= 1) {
    RED4(acc0, off2); RED4(acc1, off2); RED4(acc2, off2); RED4(acc3, off2);
  }
  if (dsub == 0) {
    int rc = rg << 2;
    if (tb + 0 < valid) *(float4*)&h[(size_t)(p0 + tb + 0) * NR + rc] = acc0;
    if (tb + 1 < valid) *(float4*)&h[(size_t)(p0 + tb + 1) * NR + rc] = acc1;
    if (tb + 2 < valid) *(float4*)&h[(size_t)(p0 + tb + 2) * NR + rc] = acc2;
    if (tb + 3 < valid) *(float4*)&h[(size_t)(p0 + tb + 3) * NR + rc] = acc3;
  }
}

// ---------------------------------------------------------------------------
// Kernel E: out[n] = lora_b[e] @ h. Tiles: 64 tokens x 256 outs.
// threads = og(32) x tokg(8); per-thread 8 tok x 8 outs (4 lo + 4 hi).
// ---------------------------------------------------------------------------
__global__ __launch_bounds__(256) void kE(const float* __restrict__ h,
    const float* __restrict__ lb, const int* __restrict__ counts,
    const int* __restrict__ bucket, float* __restrict__ out) {
  __shared__ float bt[16][260];
  __shared__ float ht[16][64];
  __shared__ int toks[64];
  int tile = blockIdx.y;
  int e = -1, jt = 0, off = 0;
  { int tot = 0, o = 0;
    #pragma unroll
    for (int i = 0; i < 8; ++i) {
      int c = counts[i]; int nt = (c + 63) >> 6;
      if (e < 0 && tile < tot + nt) { e = i; jt = tile - tot; off = o; }
      tot += nt; o += c;
    } }
  if (e < 0) return;
  int cnt = counts[e];
  int p0 = off + (jt << 6);
  int valid = min(64, cnt - (jt << 6));
  int o0 = blockIdx.x << 8;
  int t = threadIdx.x;
  if (t < 64) toks[t] = bucket[p0 + min(t, valid - 1)];
  const float* bbase = lb + ((size_t)e * NO + o0) * NR;
  #pragma unroll
  for (int kk = 0; kk < 4; ++kk) {
    int idx = (kk << 8) + t;
    int o = idx >> 2, rq = (idx & 3) << 2;
    float4 v = *(const float4*)(bbase + o * NR + rq);
    bt[rq + 0][o] = v.x; bt[rq + 1][o] = v.y; bt[rq + 2][o] = v.z; bt[rq + 3][o] = v.w;
  }
  { int tok = t >> 2, rq = (t & 3) << 2;
    float4 v = *(const float4*)(h + (size_t)(p0 + min(tok, valid - 1)) * NR + rq);
    ht[rq + 0][tok] = v.x; ht[rq + 1][tok] = v.y; ht[rq + 2][tok] = v.z; ht[rq + 3][tok] = v.w; }
  __syncthreads();
  int og = t & 31, tokg = t >> 5;
  int ob = og << 2, tb = tokg << 3;
  float4 z = make_float4(0.f,0.f,0.f,0.f);
  float4 aL0=z,aL1=z,aL2=z,aL3=z,aL4=z,aL5=z,aL6=z,aL7=z;
  float4 aH0=z,aH1=z,aH2=z,aH3=z,aH4=z,aH5=z,aH6=z,aH7=z;
  #pragma unroll
  for (int r = 0; r < 16; ++r) {
    float4 blo = *(const float4*)&bt[r][ob];
    float4 bhi = *(const float4*)&bt[r][ob + 128];
    float4 h0  = *(const float4*)&ht[r][tb];
    float4 h1  = *(const float4*)&ht[r][tb + 4];
    FMA4(aL0, h0.x, blo); FMA4(aH0, h0.x, bhi);
    FMA4(aL1, h0.y, blo); FMA4(aH1, h0.y, bhi);
    FMA4(aL2, h0.z, blo); FMA4(aH2, h0.z, bhi);
    FMA4(aL3, h0.w, blo); FMA4(aH3, h0.w, bhi);
    FMA4(aL4, h1.x, blo); FMA4(aH4, h1.x, bhi);
    FMA4(aL5, h1.y, blo); FMA4(aH5, h1.y, bhi);
    FMA4(aL6, h1.z, blo); FMA4(aH6, h1.z, bhi);
    FMA4(aL7, h1.w, blo); FMA4(aH7, h1.w, bhi);
  }
  #define ST(J, AL, AH) { int tt = tb + (J); if (tt < valid) { \
      float* p = out + (size_t)toks[tt] * NO + o0 + ob; \
      *(float4*)p = AL; *(float4*)(p + 128) = AH; } }
  ST(0, aL0, aH0); ST(1, aL1, aH1); ST(2, aL2, aH2); ST(3, aL3, aH3);
  ST(4, aL4, aH4); ST(5, aL5, aH5); ST(6, aL6, aH6); ST(7, aL7, aH7);
  #undef ST
}

// ---------------------------------------------------------------------------
extern "C" void kernel_launch(void* const* d_in, const int* in_sizes, int n_in,
                              void* d_out, int out_size, void* d_ws, size_t ws_size,
                              hipStream_t stream) {
  const float* x  = (const float*)d_in[0];
  const float* wg = (const float*)d_in[1];
  const float* wn = (const float*)d_in[2];
  const float* la = (const float*)d_in[3];
  const float* lb = (const float*)d_in[4];
  const float* nz = (const float*)d_in[5];
  float* out = (float*)d_out;

  char* ws = (char*)d_ws;
  float* h        = (float*)(ws);                 // 8192*16*4 = 524288 B
  int*   eid      = (int*)  (ws + 524288);        // 32768 B
  int*   bucket   = (int*)  (ws + 557056);        // 32768 B
  float* partials = (float*)(ws + 589824);        // 512*16*4 = 32768 B
  int*   counts   = (int*)  (ws + 622592);        // 32 B
  int*   fill     = (int*)  (ws + 622624);        // 32 B

  kA<<<512, 256, 0, stream>>>(x, wg, wn, nz, eid, partials);
  kB<<<1, 256, 0, stream>>>(partials, out + OUT_ELEMS, counts, fill);
  kC<<<32, 256, 0, stream>>>(eid, counts, fill, bucket);
  kD<<<263, 256, 0, stream>>>(x, la, counts, bucket, h);
  kE<<<dim3(12, 135), 256, 0, stream>>>(h, lb, counts, bucket, out);
}